// Round 7
// baseline (311.952 us; speedup 1.0000x reference)
//
#include <hip/hip_runtime.h>
#include <hip/hip_bf16.h>
#include <hip/hip_cooperative_groups.h>

namespace cg = cooperative_groups;

typedef __bf16 bf16x8 __attribute__((ext_vector_type(8)));
typedef float  f32x4  __attribute__((ext_vector_type(4)));

#define IN_F   4096
#define OUT_F  4096
#define RANK   32

__device__ __forceinline__ bf16x8 cvt8(float4 a, float4 b) {
    bf16x8 r;
    r[0] = (__bf16)a.x; r[1] = (__bf16)a.y; r[2] = (__bf16)a.z; r[3] = (__bf16)a.w;
    r[4] = (__bf16)b.x; r[5] = (__bf16)b.y; r[6] = (__bf16)b.z; r[7] = (__bf16)b.w;
    return r;
}

// Single cooperative kernel. 1024 blocks x 256 thr (4 waves), co-resident
// (4 blocks/CU, 16 waves/CU). Block bx: token-tile tt = bx>>1, z = bx&1.
// Phase A: H-partial for tokens [tt*16,+16) over features [z*2048,+2048)
//   -> Hpart[z][tt][16][32] in d_ws.  grid.sync().
// Phase B: Out for tokens [tt*16,+16), cols [z*2048,+2048).
__global__ __launch_bounds__(256, 4)
void lora_coop(const float* __restrict__ X, const float* __restrict__ U,
               const float* __restrict__ S, const float* __restrict__ V,
               float* __restrict__ Out, float* __restrict__ Hpart)
{
    __shared__ float Hp[4][16][RANK + 1];   // phase A per-wave partials
    __shared__ float Hs[16][RANK + 1];      // phase B reduced H

    const int tid  = threadIdx.x;
    const int wave = tid >> 6;
    const int lane = tid & 63;
    const int row  = lane & 15;
    const int kg   = lane >> 4;

    const int tt = blockIdx.x >> 1;
    const int z  = blockIdx.x & 1;
    const int t0 = tt * 16;

    // ---------------- Phase A: H partials = X_tile @ V^T ----------------
    // wave w covers features [z*2048 + w*512, +512) -> 16 MFMA K-steps
    {
        const int f0 = z * 2048 + wave * 512 + kg * 8;
        f32x4 acc0 = {0.f, 0.f, 0.f, 0.f};
        f32x4 acc1 = {0.f, 0.f, 0.f, 0.f};

        const float* xptr  = X + (size_t)(t0 + row) * IN_F + f0;
        const float* v0ptr = V + (size_t)row        * IN_F + f0;
        const float* v1ptr = V + (size_t)(16 + row) * IN_F + f0;

        #pragma unroll 4
        for (int s = 0; s < 16; ++s) {
            const float4* ap  = reinterpret_cast<const float4*>(xptr  + s * 32);
            const float4* b0p = reinterpret_cast<const float4*>(v0ptr + s * 32);
            const float4* b1p = reinterpret_cast<const float4*>(v1ptr + s * 32);
            float4 a0 = ap[0],  a1 = ap[1];
            float4 c0 = b0p[0], c1 = b0p[1];
            float4 d0 = b1p[0], d1 = b1p[1];
            bf16x8 af  = cvt8(a0, a1);
            bf16x8 bf0 = cvt8(c0, c1);
            bf16x8 bf1 = cvt8(d0, d1);
            acc0 = __builtin_amdgcn_mfma_f32_16x16x32_bf16(af, bf0, acc0, 0, 0, 0);
            acc1 = __builtin_amdgcn_mfma_f32_16x16x32_bf16(af, bf1, acc1, 0, 0, 0);
        }

        // D layout (verified): token = kg*4+j, rank = row (acc0) / 16+row (acc1)
        #pragma unroll
        for (int j = 0; j < 4; ++j) {
            Hp[wave][kg * 4 + j][row]      = acc0[j];
            Hp[wave][kg * 4 + j][16 + row] = acc1[j];
        }
    }
    __syncthreads();

    // reduce 4 wave-partials, apply S, write slice partial to workspace
    {
        float* dst = Hpart + ((size_t)z * 512 + tt) * 512;
        for (int i = tid; i < 16 * RANK; i += 256) {
            int tok = i >> 5, r = i & 31;
            float s = Hp[0][tok][r] + Hp[1][tok][r] + Hp[2][tok][r] + Hp[3][tok][r];
            dst[i] = s * S[r];              // SCALING == 1.0 folded
        }
    }

    __threadfence();                        // make Hpart visible device-wide
    cg::this_grid().sync();

    // ---------------- Phase B: Out = H @ U^T ----------------
    // reduce the 2 feature-slice partials for this token tile
    for (int i = tid; i < 16 * RANK; i += 256) {
        float s = Hpart[(size_t)tt * 512 + i]
                + Hpart[((size_t)512 + tt) * 512 + i];
        Hs[i >> 5][i & 31] = s;
    }
    __syncthreads();

    // A fragment: token = row, k(rank) = kg*8+j
    bf16x8 ha;
    #pragma unroll
    for (int j = 0; j < 8; ++j) ha[j] = (__bf16)Hs[row][kg * 8 + j];

    float* obase = Out + (size_t)(t0 + kg * 4) * OUT_F + row;

    #pragma unroll 4
    for (int i = 0; i < 32; ++i) {          // 32 tiles/wave -> 2048 cols per block
        int o0 = z * 2048 + (i * 4 + wave) * 16;
        const float4* up = reinterpret_cast<const float4*>(
            U + (size_t)(o0 + row) * RANK + kg * 8);
        float4 u0 = up[0], u1 = up[1];
        bf16x8 bu = cvt8(u0, u1);
        f32x4 d = {0.f, 0.f, 0.f, 0.f};
        d = __builtin_amdgcn_mfma_f32_16x16x32_bf16(ha, bu, d, 0, 0, 0);
        #pragma unroll
        for (int j = 0; j < 4; ++j)
            obase[(size_t)j * OUT_F + o0] = d[j];
    }
}

extern "C" void kernel_launch(void* const* d_in, const int* in_sizes, int n_in,
                              void* d_out, int out_size, void* d_ws, size_t ws_size,
                              hipStream_t stream) {
    const float* X = (const float*)d_in[0];
    const float* U = (const float*)d_in[1];
    const float* S = (const float*)d_in[2];
    const float* V = (const float*)d_in[3];
    float* Out   = (float*)d_out;
    float* Hpart = (float*)d_ws;            // 2 slices * 512 tiles * 512 floats = 2 MB

    void* args[] = { (void*)&X, (void*)&U, (void*)&S, (void*)&V,
                     (void*)&Out, (void*)&Hpart };
    hipLaunchCooperativeKernel((void*)lora_coop, dim3(1024), dim3(256),
                               args, 0, stream);
}

// Round 8
// 84.024 us; speedup vs baseline: 3.7127x; 3.7127x over previous
//
#include <hip/hip_runtime.h>
#include <hip/hip_bf16.h>

typedef __bf16 bf16x8 __attribute__((ext_vector_type(8)));
typedef float  f32x4  __attribute__((ext_vector_type(4)));

#define IN_F   4096
#define OUT_F  4096
#define RANK   32
#define CF     128            // features per K1 chunk
#define NCH    (IN_F / CF)    // 32 chunks

__device__ __forceinline__ bf16x8 cvt8(float4 a, float4 b) {
    bf16x8 r;
    r[0] = (__bf16)a.x; r[1] = (__bf16)a.y; r[2] = (__bf16)a.z; r[3] = (__bf16)a.w;
    r[4] = (__bf16)b.x; r[5] = (__bf16)b.y; r[6] = (__bf16)b.z; r[7] = (__bf16)b.w;
    return r;
}

// async global->LDS, 16 B/lane: LDS dest = uniform base + lane*16,
// global src = per-lane address (pre-permuted to match fragment layout).
__device__ __forceinline__ void gl_lds16(const float* g, void* l) {
    __builtin_amdgcn_global_load_lds(
        (const __attribute__((address_space(1))) char*)g,
        (__attribute__((address_space(3))) char*)l, 16, 0, 0);
}

// ---------------- Kernel 1: H = (X @ V^T) * S ----------------
// 512 blocks x 256 thr (4 waves). Block: 16 tokens, full 4096 features in
// 32 double-buffered chunks of 128 feats. Staging via global_load_lds into
// fragment-major LDS: XB[s][h][lane16B] where lane = q*16 + row encodes
// (row = token, q = 4-float slot within the 16-float half h of step s).
// Wave (rh = rank half, fs = step half) computes 2 MFMAs/chunk.
__global__ __launch_bounds__(256, 2)
void lora_h(const float* __restrict__ X, const float* __restrict__ S,
            const float* __restrict__ V, float* __restrict__ H)
{
    __shared__ float4 XB[2][4][2][64];      // [buf][s][h][lane]  16 KB
    __shared__ float4 VB[2][2][4][2][64];   // [buf][rh][s][h][lane] 32 KB
    __shared__ float  Hp[4][16][17];        // per-wave partials

    const int tid  = threadIdx.x;
    const int wave = tid >> 6;
    const int lane = tid & 63;
    const int r    = lane & 15;
    const int kg   = lane >> 4;
    const int t0   = blockIdx.x * 16;

    const int rh = wave & 1;
    const int fs = wave >> 1;

    const size_t xrow = (size_t)(t0 + r) * IN_F;
    const int    sub  = kg * 4;             // float offset within 16-float half

    // stage chunk c into buffer nb: 24 x 1KB instructions, 6 per wave
    auto stage = [&](int c, int nb) {
        const int fc = c * CF;
        #pragma unroll
        for (int t = 0; t < 6; ++t) {
            const int inst = wave * 6 + t;
            if (inst < 8) {                 // X: (s, h)
                const int s = inst >> 1, h = inst & 1;
                gl_lds16(X + xrow + fc + s * 32 + h * 16 + sub,
                         (void*)&XB[nb][s][h][0]);
            } else {                        // V: (vrh, s, h)
                const int v = inst - 8;
                const int vrh = v >> 3, s = (v >> 1) & 3, h = v & 1;
                gl_lds16(V + (size_t)(vrh * 16 + r) * IN_F + fc + s * 32 + h * 16 + sub,
                         (void*)&VB[nb][vrh][s][h][0]);
            }
        }
    };

    f32x4 acc = {0.f, 0.f, 0.f, 0.f};

    stage(0, 0);
    asm volatile("s_waitcnt vmcnt(0)" ::: "memory");
    __syncthreads();

    const int h  = kg >> 1;                 // half holding floats kg*8..kg*8+7
    const int qb = (kg & 1) * 2;            // first 4-float slot

    for (int c = 0; c < NCH; ++c) {
        const int cur = c & 1;
        if (c + 1 < NCH) stage(c + 1, cur ^ 1);   // issue-early

        #pragma unroll
        for (int s2 = 0; s2 < 2; ++s2) {
            const int s = fs * 2 + s2;
            float4 x0 = *(const float4*)&XB[cur][s][h][qb * 16 + r];
            float4 x1 = *(const float4*)&XB[cur][s][h][(qb + 1) * 16 + r];
            float4 v0 = *(const float4*)&VB[cur][rh][s][h][qb * 16 + r];
            float4 v1 = *(const float4*)&VB[cur][rh][s][h][(qb + 1) * 16 + r];
            // A = X (m = token = lane&15), B = V (n = rank-in-half = lane&15)
            acc = __builtin_amdgcn_mfma_f32_16x16x32_bf16(
                      cvt8(x0, x1), cvt8(v0, v1), acc, 0, 0, 0);
        }

        asm volatile("s_waitcnt vmcnt(0)" ::: "memory");  // wait-late: prefetch hidden under compute
        __syncthreads();
    }

    // D: n(rank) = lane&15, m(token) = kg*4+j
    #pragma unroll
    for (int j = 0; j < 4; ++j) Hp[wave][kg * 4 + j][r] = acc[j];
    __syncthreads();

    // combine fs-halves, apply S (SCALING == 1.0 folded)
    for (int i = tid; i < 16 * RANK; i += 256) {
        const int tok = i >> 5, rr = i & 31;
        const int rhh = rr >> 4, ri = rr & 15;
        const float s = Hp[rhh][tok][ri] + Hp[2 + rhh][tok][ri];
        H[(size_t)(t0 + tok) * RANK + rr] = s * S[rr];
    }
}

// ---------------- Kernel 2: Out = H @ U^T ----------------
// 4096 blocks x 256 thr. Block: 128 tokens x 64 cols. Loads strictly first
// (U frags -> regs, H -> LDS), then pure MFMA + float4 stores (swapped
// operands: A = U so D rows are contiguous output columns).
__global__ __launch_bounds__(256, 4)
void lora_out(const float* __restrict__ H, const float* __restrict__ U,
              float* __restrict__ Out)
{
    __shared__ float Hs[128][33];

    const int tid  = threadIdx.x;
    const int wave = tid >> 6;
    const int lane = tid & 63;
    const int r    = lane & 15;
    const int kg   = lane >> 4;

    const int tt = blockIdx.x >> 6;
    const int cq = blockIdx.x & 63;
    const int t0 = tt * 128;
    const int c0 = cq * 64;

    // batched U fragment loads (L2-resident, 8 x 16B per lane)
    float4 ua[4][2];
    #pragma unroll
    for (int b = 0; b < 4; ++b) {
        const float4* up = reinterpret_cast<const float4*>(
            U + (size_t)(c0 + b * 16 + r) * RANK + kg * 8);
        ua[b][0] = up[0];
        ua[b][1] = up[1];
    }

    // H tile -> LDS (16 KB, coalesced float4 stream)
    const float4* hsrc = reinterpret_cast<const float4*>(H + (size_t)t0 * RANK);
    #pragma unroll
    for (int k = 0; k < 4; ++k) {
        const int fidx = tid + k * 256;     // float4 index 0..1023
        float4 v = hsrc[fidx];
        const int tok = fidx >> 3;
        const int rr  = (fidx & 7) * 4;
        Hs[tok][rr] = v.x; Hs[tok][rr + 1] = v.y;
        Hs[tok][rr + 2] = v.z; Hs[tok][rr + 3] = v.w;
    }
    __syncthreads();

    bf16x8 ub[4];
    #pragma unroll
    for (int b = 0; b < 4; ++b) ub[b] = cvt8(ua[b][0], ua[b][1]);

    // compute + store phase: no loads -> stores never gate on vmcnt of loads
    #pragma unroll
    for (int ai = 0; ai < 2; ++ai) {
        const int a = wave + ai * 4;        // token tile 0..7
        bf16x8 hb;
        #pragma unroll
        for (int j = 0; j < 8; ++j) hb[j] = (__bf16)Hs[a * 16 + r][kg * 8 + j];
        float* orow = Out + (size_t)(t0 + a * 16 + r) * OUT_F + c0 + kg * 4;
        #pragma unroll
        for (int b = 0; b < 4; ++b) {
            f32x4 d = {0.f, 0.f, 0.f, 0.f};
            // A = U (m = outcol), B = H (n = token); D: lane j -> col kg*4+j
            d = __builtin_amdgcn_mfma_f32_16x16x32_bf16(ub[b], hb, d, 0, 0, 0);
            *reinterpret_cast<float4*>(orow + b * 16) = *reinterpret_cast<float4*>(&d);
        }
    }
}

extern "C" void kernel_launch(void* const* d_in, const int* in_sizes, int n_in,
                              void* d_out, int out_size, void* d_ws, size_t ws_size,
                              hipStream_t stream) {
    const float* X = (const float*)d_in[0];
    const float* U = (const float*)d_in[1];
    const float* S = (const float*)d_in[2];
    const float* V = (const float*)d_in[3];
    float* Out = (float*)d_out;
    float* Hws = (float*)d_ws;              // H: 8192 x 32 fp32 = 1 MB

    lora_h  <<<512,  256, 0, stream>>>(X, S, V, Hws);
    lora_out<<<4096, 256, 0, stream>>>(Hws, U, Out);
}